// Round 10
// baseline (416.729 us; speedup 1.0000x reference)
//
#include <hip/hip_runtime.h>
#include <hip/hip_bf16.h>
#include <math.h>

#define NHEAD 4
#define HC 256

typedef short short8 __attribute__((ext_vector_type(8)));
typedef short short4v __attribute__((ext_vector_type(4)));
typedef float f32x4 __attribute__((ext_vector_type(4)));

__device__ inline f32x4 bf4_to_f32(short4v v)
{
  f32x4 r;
#pragma unroll
  for (int i = 0; i < 4; ++i)
    r[i] = __uint_as_float(((unsigned)(unsigned short)v[i]) << 16);
  return r;
}

__device__ inline float bf_to_f32(unsigned short u)
{
  return __uint_as_float(((unsigned)u) << 16);
}

__device__ inline short4v f4_to_bf4(f32x4 v)
{
  short4v o;
#pragma unroll
  for (int i = 0; i < 4; ++i) {
    __hip_bfloat16 h = __float2bfloat16(v[i]);
    o[i] = *(short*)&h;
  }
  return o;
}

// DPP rotate-add within a row of 16 lanes (VALU-only).
template <int CTRL>
__device__ inline float dpp_radd(float x)
{
  int yi = __builtin_amdgcn_update_dpp(0, __float_as_int(x), CTRL, 0xf, 0xf, true);
  return x + __int_as_float(yi);
}

// ------- one fused prep kernel -------
// R20: x/fp conversions vectorized; fwt transpose folded in.
// R23: k1wt is now a STRAIGHT bf16 copy of k1W (k-major [384][192]) —
// head123 stages K-chunks from it coalesced and reads LDS conflict-free.
__global__ void prep_kernel(
    const float* __restrict__ x, const float* __restrict__ fp,
    const float* __restrict__ c1Wl, const float* __restrict__ c1Wr,
    const float* __restrict__ c2Wl, const float* __restrict__ c2Wr,
    const float* __restrict__ desc, const float* __restrict__ dW,
    const float* __restrict__ k1W, const float* __restrict__ fW,
    const int* __restrict__ dst, int* __restrict__ deg,
    __hip_bfloat16* __restrict__ xbf, __hip_bfloat16* __restrict__ fpbf,
    __hip_bfloat16* __restrict__ wt1, __hip_bfloat16* __restrict__ wt2,
    __hip_bfloat16* __restrict__ descbf, __hip_bfloat16* __restrict__ dwt,
    __hip_bfloat16* __restrict__ k1wt, __hip_bfloat16* __restrict__ fwt,
    int N, int G, int E, int DIN)
{
  const int n0 = N * 8;       // x as vec4 (N*32/4)
  const int n1 = G * 512;     // fp as vec4 (G*2048/4)
  const int n2 = 512 * 32, n3 = 512 * 256;
  const int n4 = G * 224, n5 = 64 * 224, n6 = 384 * 192;
  const int n7 = 256 * 2048; // fwt transpose
  int idx = blockIdx.x * 256 + threadIdx.x;
  if (idx < n0) {
    f32x4 v = ((const f32x4*)x)[idx];
    ((short4v*)xbf)[idx] = f4_to_bf4(v);
    return;
  }
  idx -= n0;
  if (idx < n1) {
    f32x4 v = ((const f32x4*)fp)[idx];
    ((short4v*)fpbf)[idx] = f4_to_bf4(v);
    return;
  }
  idx -= n1;
  if (idx < n2) {
    int n = idx / 32, k = idx - n * 32;
    float v = (n < 256) ? c1Wl[k * 256 + n] : c1Wr[k * 256 + (n - 256)];
    wt1[idx] = __float2bfloat16(v); return;
  }
  idx -= n2;
  if (idx < n3) {
    int n = idx / 256, k = idx - n * 256;
    float v = (n < 256) ? c2Wl[k * 256 + n] : c2Wr[k * 256 + (n - 256)];
    wt2[idx] = __float2bfloat16(v); return;
  }
  idx -= n3;
  if (idx < n4) {
    int row = idx / 224, kp = idx - row * 224;
    float v = (kp < DIN) ? desc[(long)row * DIN + kp] : 0.f;
    descbf[idx] = __float2bfloat16(v); return;
  }
  idx -= n4;
  if (idx < n5) {
    int n = idx / 224, kp = idx - n * 224;
    float v = (kp < DIN) ? dW[kp * 64 + n] : 0.f;
    dwt[idx] = __float2bfloat16(v); return;
  }
  idx -= n5;
  if (idx < n6) {
    k1wt[idx] = __float2bfloat16(k1W[idx]); return;   // k-major straight copy
  }
  idx -= n6;
  if (idx < n7) {
    int n = idx >> 11, k = idx & 2047;   // fwt[n][k] = fW[k][n]
    fwt[idx] = __float2bfloat16(fW[k * 256 + n]); return;
  }
  idx -= n7;
  if (idx < E) atomicAdd(&deg[dst[idx]], 1);
}

// ------- R23 fused CSR scan: one 1024-thread block, 32-elem strips --------
// Replaces scan1+scan2 (2 dispatches -> 1). Each thread owns deg[t*32..t*32+32);
// LDS scan of the 1024 strip sums; write ptr/cursor + ptr[N].
__global__ __launch_bounds__(1024) void scan_kernel(
    const int* __restrict__ deg, int* __restrict__ ptr,
    int* __restrict__ cursor, int N)
{
  __shared__ int s[1024];
  int t = threadIdx.x;
  int base = t * 32;
  int local[32];
  int sum = 0;
#pragma unroll
  for (int j = 0; j < 32; ++j) { local[j] = deg[base + j]; sum += local[j]; }
  s[t] = sum;
  __syncthreads();
  for (int off = 1; off < 1024; off <<= 1) {
    int xv = (t >= off) ? s[t - off] : 0;
    __syncthreads();
    s[t] += xv;
    __syncthreads();
  }
  int run = (t > 0) ? s[t - 1] : 0;
#pragma unroll
  for (int j = 0; j < 32; ++j) {
    ptr[base + j] = run;
    cursor[base + j] = run;
    run += local[j];
  }
  if (t == 1023) ptr[N] = s[1023];
}

// ------- bf16 MFMA GEMM: [xl|xr] = A[M][K] @ W[K][512] + bias -> bf16 tables
// (used standalone for layer 2; layer 1 is folded into mega1)
__global__ __launch_bounds__(256) void gemm_mfma_kernel(
    const __hip_bfloat16* __restrict__ A, const __hip_bfloat16* __restrict__ BT,
    const float* __restrict__ bl, const float* __restrict__ br,
    __hip_bfloat16* __restrict__ XL, __hip_bfloat16* __restrict__ XR, int M, int K)
{
  __shared__ short As[128 * 40];
  __shared__ short Bs[128 * 40];
  int bm = blockIdx.x * 128, bn = blockIdx.y * 128;
  int t = threadIdx.x;
  int w = t >> 6, l = t & 63;
  int quad = l >> 4, l16 = l & 15;
  int srow = t >> 1, scol = (t & 1) * 16;

  f32x4 acc[2][8];
#pragma unroll
  for (int i = 0; i < 2; ++i)
#pragma unroll
    for (int j = 0; j < 8; ++j) acc[i][j] = (f32x4){0.f, 0.f, 0.f, 0.f};

  for (int k0 = 0; k0 < K; k0 += 32) {
    *(short8*)&As[srow * 40 + scol] =
        *(const short8*)(const void*)&A[(long)(bm + srow) * K + k0 + scol];
    *(short8*)&As[srow * 40 + scol + 8] =
        *(const short8*)(const void*)&A[(long)(bm + srow) * K + k0 + scol + 8];
    *(short8*)&Bs[srow * 40 + scol] =
        *(const short8*)(const void*)&BT[(long)(bn + srow) * K + k0 + scol];
    *(short8*)&Bs[srow * 40 + scol + 8] =
        *(const short8*)(const void*)&BT[(long)(bn + srow) * K + k0 + scol + 8];
    __syncthreads();
    short8 af[2], bf[8];
#pragma unroll
    for (int mt = 0; mt < 2; ++mt)
      af[mt] = *(short8*)&As[(w * 32 + mt * 16 + l16) * 40 + quad * 8];
#pragma unroll
    for (int nt = 0; nt < 8; ++nt)
      bf[nt] = *(short8*)&Bs[(nt * 16 + l16) * 40 + quad * 8];
#pragma unroll
    for (int mt = 0; mt < 2; ++mt)
#pragma unroll
      for (int nt = 0; nt < 8; ++nt)
        acc[mt][nt] = __builtin_amdgcn_mfma_f32_16x16x32_bf16(af[mt], bf[nt], acc[mt][nt], 0, 0, 0);
    __syncthreads();
  }
#pragma unroll
  for (int mt = 0; mt < 2; ++mt)
#pragma unroll
    for (int nt = 0; nt < 8; ++nt) {
      int col = bn + nt * 16 + l16;
      float b = (col < 256) ? bl[col] : br[col - 256];
#pragma unroll
      for (int r = 0; r < 4; ++r) {
        int row = bm + w * 32 + mt * 16 + quad * 4 + r;
        float v = acc[mt][nt][r] + b;
        if (col < 256)
          XL[(long)row * 256 + col] = __float2bfloat16(v);
        else
          XR[(long)row * 256 + (col - 256)] = __float2bfloat16(v);
      }
    }
}

// ------- MEGA1: CSR fill ∪ layer-1 transform GEMM ∪ fp split-K GEMM ∪ desc
// GEMM. All depend only on prep+scan. One dispatch: fill's scatter/atomic
// latency hides under the MFMA compute of the other ranges (R21). -----
__global__ __launch_bounds__(256) void mega1_kernel(
    const int* __restrict__ esrc, const int* __restrict__ edst,
    const float* __restrict__ ea, int* __restrict__ cursor,
    int* __restrict__ csr_src, float* __restrict__ csr_ea,
    const __hip_bfloat16* __restrict__ xbf, const __hip_bfloat16* __restrict__ wt1,
    const float* __restrict__ c1_bl, const float* __restrict__ c1_br,
    __hip_bfloat16* __restrict__ xlb, __hip_bfloat16* __restrict__ xrb,
    const __hip_bfloat16* __restrict__ fpbf, const __hip_bfloat16* __restrict__ fwt,
    float* __restrict__ P,
    const __hip_bfloat16* __restrict__ descbf, const __hip_bfloat16* __restrict__ dwt,
    const float* __restrict__ db, const float* __restrict__ d_gn,
    const float* __restrict__ d_bt, __hip_bfloat16* __restrict__ zbuf,
    int N, int G, int E)
{
  __shared__ short As[128 * 40];
  __shared__ short Bs[128 * 40];
  int b = blockIdx.x;
  const int t = threadIdx.x;
  const int NB_FILL = E / 256;          // 1024
  const int GX1 = N / 128;              // 256
  const int NB_GEMM1 = GX1 * 4;         // 1024
  const int NB_SKB = (G / 64) * 16;     // 256

  if (b < NB_FILL) {
    // ---- CSR fill: scatter src + edge_attr ----
    int e = b * 256 + t;
    if (e < E) {
      int pos = atomicAdd(&cursor[edst[e]], 1);
      csr_src[pos] = esrc[e];
      f32x4 a0 = *(const f32x4*)(const void*)&ea[(long)e * 8];
      f32x4 a1 = *(const f32x4*)(const void*)&ea[(long)e * 8 + 4];
      *(f32x4*)&csr_ea[(long)pos * 8] = a0;
      *(f32x4*)&csr_ea[(long)pos * 8 + 4] = a1;
    }
    return;
  }
  b -= NB_FILL;
  if (b < NB_GEMM1) {
    // ---- layer-1 transform GEMM: [xl|xr] = xbf @ wt1 + bias, K=32 ----
    int bx = b % GX1, by = b / GX1;
    int bm = bx * 128, bn = by * 128;
    const int K = 32;
    int w = t >> 6, l = t & 63;
    int quad = l >> 4, l16 = l & 15;
    int srow = t >> 1, scol = (t & 1) * 16;

    f32x4 acc[2][8];
#pragma unroll
    for (int i = 0; i < 2; ++i)
#pragma unroll
      for (int j = 0; j < 8; ++j) acc[i][j] = (f32x4){0.f, 0.f, 0.f, 0.f};

    {
      const int k0 = 0;
      *(short8*)&As[srow * 40 + scol] =
          *(const short8*)(const void*)&xbf[(long)(bm + srow) * K + k0 + scol];
      *(short8*)&As[srow * 40 + scol + 8] =
          *(const short8*)(const void*)&xbf[(long)(bm + srow) * K + k0 + scol + 8];
      *(short8*)&Bs[srow * 40 + scol] =
          *(const short8*)(const void*)&wt1[(long)(bn + srow) * K + k0 + scol];
      *(short8*)&Bs[srow * 40 + scol + 8] =
          *(const short8*)(const void*)&wt1[(long)(bn + srow) * K + k0 + scol + 8];
      __syncthreads();
      short8 af[2], bf[8];
#pragma unroll
      for (int mt = 0; mt < 2; ++mt)
        af[mt] = *(short8*)&As[(w * 32 + mt * 16 + l16) * 40 + quad * 8];
#pragma unroll
      for (int nt = 0; nt < 8; ++nt)
        bf[nt] = *(short8*)&Bs[(nt * 16 + l16) * 40 + quad * 8];
#pragma unroll
      for (int mt = 0; mt < 2; ++mt)
#pragma unroll
        for (int nt = 0; nt < 8; ++nt)
          acc[mt][nt] = __builtin_amdgcn_mfma_f32_16x16x32_bf16(af[mt], bf[nt], acc[mt][nt], 0, 0, 0);
    }
#pragma unroll
    for (int mt = 0; mt < 2; ++mt)
#pragma unroll
      for (int nt = 0; nt < 8; ++nt) {
        int col = bn + nt * 16 + l16;
        float bb = (col < 256) ? c1_bl[col] : c1_br[col - 256];
#pragma unroll
        for (int r = 0; r < 4; ++r) {
          int row = bm + w * 32 + mt * 16 + quad * 4 + r;
          float v = acc[mt][nt][r] + bb;
          if (col < 256)
            xlb[(long)row * 256 + col] = __float2bfloat16(v);
          else
            xrb[(long)row * 256 + (col - 256)] = __float2bfloat16(v);
        }
      }
    return;
  }
  b -= NB_GEMM1;
  if (b < NB_SKB) {
    // ---- fp branch split-K GEMM: P[s] = fpbf @ fwt (K-slice) ----
    const int gx = G / 64;
    int bx = b % gx, rem = b / gx;
    int by = rem & 3, s = rem >> 2;
    int bm = bx * 64, bn = by * 64;
    const int K = 2048, Kc = 512;
    int kb = s * Kc, ke = kb + Kc;
    int w = t >> 6, l = t & 63;
    int quad = l >> 4, l16 = l & 15;
    int lrow = t >> 2, col8 = (t & 3) * 8;

    f32x4 acc[4];
#pragma unroll
    for (int nt = 0; nt < 4; ++nt) acc[nt] = (f32x4){0.f, 0.f, 0.f, 0.f};

    for (int k0 = kb; k0 < ke; k0 += 32) {
      *(short8*)&As[lrow * 40 + col8] =
          *(const short8*)(const void*)&fpbf[(long)(bm + lrow) * K + k0 + col8];
      *(short8*)&Bs[lrow * 40 + col8] =
          *(const short8*)(const void*)&fwt[(long)(bn + lrow) * K + k0 + col8];
      __syncthreads();
      short8 af = *(short8*)&As[(w * 16 + l16) * 40 + quad * 8];
#pragma unroll
      for (int nt = 0; nt < 4; ++nt) {
        short8 bf = *(short8*)&Bs[(nt * 16 + l16) * 40 + quad * 8];
        acc[nt] = __builtin_amdgcn_mfma_f32_16x16x32_bf16(af, bf, acc[nt], 0, 0, 0);
      }
      __syncthreads();
    }
#pragma unroll
    for (int nt = 0; nt < 4; ++nt) {
      int col = bn + nt * 16 + l16;
#pragma unroll
      for (int r = 0; r < 4; ++r) {
        int row = bm + w * 16 + quad * 4 + r;
        P[((long)s * G + row) * 256 + col] = acc[nt][r];
      }
    }
    return;
  }
  b -= NB_SKB;
  {
    // ---- desc branch GEMM + relu + bn -> zbuf[:,320:384] bf16 ----
    int bm = b * 64;
    const int K = 224;
    int w = t >> 6, l = t & 63;
    int quad = l >> 4, l16 = l & 15;
    int lrow = t >> 2, col8 = (t & 3) * 8;

    f32x4 acc[4];
#pragma unroll
    for (int nt = 0; nt < 4; ++nt) acc[nt] = (f32x4){0.f, 0.f, 0.f, 0.f};

    for (int k0 = 0; k0 < K; k0 += 32) {
      *(short8*)&As[lrow * 40 + col8] =
          *(const short8*)(const void*)&descbf[(long)(bm + lrow) * K + k0 + col8];
      *(short8*)&Bs[lrow * 40 + col8] =
          *(const short8*)(const void*)&dwt[(long)lrow * K + k0 + col8];
      __syncthreads();
      short8 af = *(short8*)&As[(w * 16 + l16) * 40 + quad * 8];
#pragma unroll
      for (int nt = 0; nt < 4; ++nt) {
        short8 bf = *(short8*)&Bs[(nt * 16 + l16) * 40 + quad * 8];
        acc[nt] = __builtin_amdgcn_mfma_f32_16x16x32_bf16(af, bf, acc[nt], 0, 0, 0);
      }
      __syncthreads();
    }
    const float inv = rsqrtf(1.f + 1e-5f);
#pragma unroll
    for (int nt = 0; nt < 4; ++nt) {
      int col = nt * 16 + l16;   // bn = 0, 64 cols
      float bb = db[col], gm = d_gn[col] * inv, bt = d_bt[col];
#pragma unroll
      for (int r = 0; r < 4; ++r) {
        int row = bm + w * 16 + quad * 4 + r;
        float v = fmaxf(acc[nt][r] + bb, 0.f) * gm + bt;
        zbuf[(long)row * 384 + 320 + col] = __float2bfloat16(v);
      }
    }
  }
}

// ------- MEGA2: eamean (gather-latency) ∪ fp split-K epilogue (streaming) ---
__global__ __launch_bounds__(256) void mega2_kernel(
    const float* __restrict__ csr_ea, const int* __restrict__ csr_ptr,
    float* __restrict__ ea_mean,
    const float* __restrict__ P, const float* __restrict__ fb,
    const float* __restrict__ f_gn, const float* __restrict__ f_bt,
    __hip_bfloat16* __restrict__ zbuf, int N, int G)
{
  int b = blockIdx.x;
  int t = threadIdx.x;
  const int NB_EA = N * 8 / 256;   // 1024
  if (b < NB_EA) {
    int idx = b * 256 + t;
    int node = idx >> 3, d = idx & 7;
    int p0 = csr_ptr[node], p1 = csr_ptr[node + 1];
    float s = 0.f;
    for (int k = p0; k < p1; ++k) s += csr_ea[(long)k * 8 + d];
    int cnt = p1 - p0;
    ea_mean[idx] = s / (float)(cnt > 1 ? cnt : 1);
    return;
  }
  b -= NB_EA;
  int idx = b * 256 + t;           // over G*256
  int row = idx >> 8, col = idx & 255;
  float v = 0.f;
#pragma unroll
  for (int s = 0; s < 4; ++s) v += P[(long)s * G * 256 + idx];
  const float inv = rsqrtf(1.f + 1e-5f);
  v = fmaxf(v + fb[col], 0.f) * (f_gn[col] * inv) + f_bt[col];
  zbuf[(long)row * 384 + 64 + col] = __float2bfloat16(v);
}

// -------- fused pool + g branch: per-graph colmax (LDS) -> 64-col dense -----
__global__ __launch_bounds__(256) void poolg_kernel(
    const __hip_bfloat16* __restrict__ h, const float* __restrict__ gW,
    const float* __restrict__ gb, const float* __restrict__ g_gn,
    const float* __restrict__ g_bt, __hip_bfloat16* __restrict__ zbuf, int npg)
{
  __shared__ float smax[256];
  __shared__ float sred[256];
  int g = blockIdx.x, t = threadIdx.x;
  const __hip_bfloat16* base = h + (long)g * npg * HC + t;
  float m = -INFINITY;
#pragma unroll 4
  for (int i = 0; i < npg; ++i)
    m = fmaxf(m, bf_to_f32(*(const unsigned short*)&base[(long)i * HC]));
  smax[t] = m;
  __syncthreads();
  int j = t >> 2, part = t & 3;
  float sum = 0.f;
#pragma unroll 4
  for (int k = part * 64; k < part * 64 + 64; ++k)
    sum = fmaf(smax[k], gW[k * 64 + j], sum);
  sred[t] = sum;
  __syncthreads();
  if (t < 64) {
    float v = sred[t * 4] + sred[t * 4 + 1] + sred[t * 4 + 2] + sred[t * 4 + 3];
    const float inv = rsqrtf(1.f + 1e-5f);
    v = fmaxf(v + gb[t], 0.f) * (g_gn[t] * inv) + g_bt[t];
    zbuf[(long)g * 384 + t] = __float2bfloat16(v);
  }
}

// -------- R23 fused k1+k2+k3 head: zbuf(bf16) -> d_out, 8 graphs/block -----
// Replaces gemm_rb(k1)+head23 (2 dispatches -> 1); kills the z1 roundtrip.
// R8 lesson applied: every weight operand LDS-staged before its phase; k1
// chunk stored K-MAJOR so lane-consecutive cols hit consecutive dwords
// (2-way conflict = free); wbuf shared byte-exactly between k1's bf16 chunk
// (96x192x2B) and k2's f32 half (96x96x4B) = 36.9KB. Total LDS 61.5KB.
__global__ __launch_bounds__(256) void head123_kernel(
    const __hip_bfloat16* __restrict__ zbuf, const __hip_bfloat16* __restrict__ k1wt,
    const float* __restrict__ k1b, const float* __restrict__ k1_gn,
    const float* __restrict__ k1_bt,
    const float* __restrict__ k2W, const float* __restrict__ k2b,
    const float* __restrict__ k2_gn, const float* __restrict__ k2_bt,
    const float* __restrict__ k3W, const float* __restrict__ k3b,
    float* __restrict__ out)
{
  __shared__ float sz[8 * 384];     // 12 KB
  __shared__ float wbuf[9216];      // 36.9 KB (bf16 k1 chunk / f32 k2 half)
  __shared__ float s1[8 * 192];     // 6 KB
  __shared__ float s2[8 * 96];      // 3 KB
  __shared__ float sk3[96 * 12];    // 4.6 KB
  int b = blockIdx.x, t = threadIdx.x;

  for (int i = t; i < 8 * 384; i += 256)
    sz[i] = bf_to_f32(*(const unsigned short*)&zbuf[(long)b * (8 * 384) + i]);
  for (int i = t; i < 96 * 12; i += 256) sk3[i] = k3W[i];

  // ---- k1: 8x384 @ 384x192, 4 K-chunks of 96 (k1wt k-major [384][192]) ----
  int row1[6], col1[6];
  float acc1[6];
#pragma unroll
  for (int o = 0; o < 6; ++o) {
    int idx = o * 256 + t;
    row1[o] = idx / 192; col1[o] = idx - row1[o] * 192;
    acc1[o] = 0.f;
  }
  short* ws = (short*)wbuf;
  for (int c = 0; c < 4; ++c) {
    __syncthreads();
    // stage K-major: ws[kk*192 + n] = k1wt[(c*96+kk)*192 + n]  (coalesced)
    for (int i = t; i < 96 * 192; i += 256)
      ws[i] = *(const short*)&k1wt[(long)c * 96 * 192 + i];
    __syncthreads();
#pragma unroll 4
    for (int kk = 0; kk < 96; ++kk) {
#pragma unroll
      for (int o = 0; o < 6; ++o)
        acc1[o] = fmaf(sz[row1[o] * 384 + c * 96 + kk],
                       bf_to_f32((unsigned short)ws[kk * 192 + col1[o]]), acc1[o]);
    }
  }
  const float inv = rsqrtf(1.f + 1e-5f);
#pragma unroll
  for (int o = 0; o < 6; ++o) {
    float v = fmaxf(acc1[o] + k1b[col1[o]], 0.f) * (k1_gn[col1[o]] * inv) + k1_bt[col1[o]];
    s1[row1[o] * 192 + col1[o]] = v;
  }

  // ---- k2: 8x192 @ 192x96 in 2 K-halves of 96 (f32 staged in wbuf) ----
  int row2[3], col2[3];
  float acc2[3];
#pragma unroll
  for (int o = 0; o < 3; ++o) {
    int idx = o * 256 + t;
    row2[o] = idx / 96; col2[o] = idx - row2[o] * 96;
    acc2[o] = 0.f;
  }
  for (int half = 0; half < 2; ++half) {
    __syncthreads();   // k1's wbuf reads + s1 writes complete before restage
    for (int i = t; i < 96 * 96; i += 256)
      wbuf[i] = k2W[(long)half * 96 * 96 + i];
    __syncthreads();
#pragma unroll 4
    for (int k = 0; k < 96; ++k) {
#pragma unroll
      for (int o = 0; o < 3; ++o)
        acc2[o] = fmaf(s1[row2[o] * 192 + half * 96 + k], wbuf[k * 96 + col2[o]], acc2[o]);
    }
  }
#pragma unroll
  for (int o = 0; o < 3; ++o) {
    float v = fmaxf(acc2[o] + k2b[col2[o]], 0.f) * (k2_gn[col2[o]] * inv) + k2_bt[col2[o]];
    s2[o * 256 + t] = v;   // idx == row2*96+col2
  }
  __syncthreads();
  // ---- k3: 8x96 @ 96x12 ----
  if (t < 96) {
    int r3 = t / 12, c3 = t - r3 * 12;
    float a = 0.f;
#pragma unroll 4
    for (int k = 0; k < 96; ++k) a = fmaf(s2[r3 * 96 + k], sk3[k * 12 + c3], a);
    out[(long)(b * 8 + r3) * 12 + c3] = a + k3b[c3];
  }
}

// ---------------- GATv2 aggregation ----------------
// FROZEN since R19: byte-for-byte the R1 version — the measured optimum
// across R1-R5 (61.2us, VGPR=64). Lessons: (a) must sit at VGPR<=64 (m69
// cliff), allocator lands there naturally ONLY with this structure; (b)
// never min-waves launch_bounds here; (c) occupancy is dispatch-limited at
// ~2.8 waves/SIMD regardless of geometry.
__global__ __launch_bounds__(128) void gat_kernel(
    const __hip_bfloat16* __restrict__ xlb, const __hip_bfloat16* __restrict__ xrb,
    const float* __restrict__ csr_ea, const int* __restrict__ csr_src,
    const int* __restrict__ csr_ptr, const float* __restrict__ ea_mean,
    const float* __restrict__ We, const float* __restrict__ att,
    const float* __restrict__ bias, __hip_bfloat16* __restrict__ out, int N)
{
  int lane = threadIdx.x & 63;
  int node = blockIdx.x * 2 + (threadIdx.x >> 6);
  if (node >= N) return;
  int cbase = (lane >> 4) * 64 + (lane & 15) * 4;  // channel offset in [0,256)

  f32x4 attv = *(const f32x4*)(const void*)&att[cbase];
  f32x4 xriv = bf4_to_f32(*(const short4v*)(const void*)&xrb[(long)node * HC + cbase]);
  f32x4 WeR[8];
#pragma unroll
  for (int d = 0; d < 8; ++d)
    WeR[d] = *(const f32x4*)(const void*)&We[d * HC + cbase];

  float rsumA = 0.f, rsumB = 0.f;
  f32x4 accA = (f32x4){0.f, 0.f, 0.f, 0.f};
  f32x4 accB = (f32x4){0.f, 0.f, 0.f, 0.f};

  int p0 = csr_ptr[node], p1 = csr_ptr[node + 1];

  auto edge_compute = [&](f32x4 xls, f32x4 ea0, f32x4 ea1,
                          float& rsum, f32x4& acc) {
    f32x4 mv = xriv + xls;
#pragma unroll
    for (int d = 0; d < 4; ++d) mv += WeR[d] * ea0[d];
#pragma unroll
    for (int d = 0; d < 4; ++d) mv += WeR[d + 4] * ea1[d];
    float t = 0.f;
#pragma unroll
    for (int r = 0; r < 4; ++r) {
      float m = mv[r];
      m = (m > 0.f) ? m : 0.2f * m;
      t = fmaf(m, attv[r], t);
    }
    t = dpp_radd<0x121>(t);
    t = dpp_radd<0x122>(t);
    t = dpp_radd<0x124>(t);
    t = dpp_radd<0x128>(t);
    float p = __expf(t);
    rsum += p;
    acc += p * xls;
  };

  // data slots A/B/C hold edge k,k+1,k+2 payloads; s3A/s3B/s3C hold src
  // indices for edges k+3,k+4,k+5 (one full group ahead).
  short4v xA = (short4v){0, 0, 0, 0}, xB = xA, xC = xA;
  f32x4 a0A = (f32x4){0.f, 0.f, 0.f, 0.f}, a1A = a0A;
  f32x4 a0B = a0A, a1B = a0A, a0C = a0A, a1C = a0A;
  int s3A = 0, s3B = 0, s3C = 0;

  // prologue: issue all 6 src loads (independent), then ea loads, then the
  // first 3 gathers (these wait once on the first src loads — the only
  // dependent stall per node).
  int s0 = 0, s1 = 0, s2 = 0;
  if (p0 < p1)     s0 = csr_src[p0];
  if (p0 + 1 < p1) s1 = csr_src[p0 + 1];
  if (p0 + 2 < p1) s2 = csr_src[p0 + 2];
  if (p0 + 3 < p1) s3A = csr_src[p0 + 3];
  if (p0 + 4 < p1) s3B = csr_src[p0 + 4];
  if (p0 + 5 < p1) s3C = csr_src[p0 + 5];
  if (p0 < p1) {
    a0A = *(const f32x4*)(const void*)&csr_ea[(long)p0 * 8];
    a1A = *(const f32x4*)(const void*)&csr_ea[(long)p0 * 8 + 4];
    xA = *(const short4v*)(const void*)&xlb[(long)s0 * HC + cbase];
  }
  if (p0 + 1 < p1) {
    a0B = *(const f32x4*)(const void*)&csr_ea[(long)(p0 + 1) * 8];
    a1B = *(const f32x4*)(const void*)&csr_ea[(long)(p0 + 1) * 8 + 4];
    xB = *(const short4v*)(const void*)&xlb[(long)s1 * HC + cbase];
  }
  if (p0 + 2 < p1) {
    a0C = *(const f32x4*)(const void*)&csr_ea[(long)(p0 + 2) * 8];
    a1C = *(const f32x4*)(const void*)&csr_ea[(long)(p0 + 2) * 8 + 4];
    xC = *(const short4v*)(const void*)&xlb[(long)s2 * HC + cbase];
  }

  int k = p0;
  for (; k + 3 <= p1; k += 3) {
    // ---- slot A: edge k; refill edge k+3 (src already in s3A); prefetch
    //      src for edge k+6 into s3A ----
    f32x4 e0 = a0A, e1 = a1A;
    short4v xc = xA;
    if (k + 3 < p1) {
      xA = *(const short4v*)(const void*)&xlb[(long)s3A * HC + cbase];
      a0A = *(const f32x4*)(const void*)&csr_ea[(long)(k + 3) * 8];
      a1A = *(const f32x4*)(const void*)&csr_ea[(long)(k + 3) * 8 + 4];
    }
    if (k + 6 < p1) s3A = csr_src[k + 6];
    edge_compute(bf4_to_f32(xc), e0, e1, rsumA, accA);

    // ---- slot B: edge k+1; refill k+4; src for k+7 ----
    e0 = a0B; e1 = a1B; xc = xB;
    if (k + 4 < p1) {
      xB = *(const short4v*)(const void*)&xlb[(long)s3B * HC + cbase];
      a0B = *(const f32x4*)(const void*)&csr_ea[(long)(k + 4) * 8];
      a1B = *(const f32x4*)(const void*)&csr_ea[(long)(k + 4) * 8 + 4];
    }
    if (k + 7 < p1) s3B = csr_src[k + 7];
    edge_compute(bf4_to_f32(xc), e0, e1, rsumB, accB);

    // ---- slot C: edge k+2; refill k+5; src for k+8 ----
    e0 = a0C; e1 = a1C; xc = xC;
    if (k + 5 < p1) {
      xC = *(const short4v*)(const void*)&xlb[(long)s3C * HC + cbase];
      a0C = *(const f32x4*)(const void*)&csr_ea[(long)(k + 5) * 8];
      a1C = *(const f32x4*)(const void*)&csr_ea[(long)(k + 5) * 8 + 4];
    }
    if (k + 8 < p1) s3C = csr_src[k + 8];
    edge_compute(bf4_to_f32(xc), e0, e1, rsumA, accA);
  }
  // tail (0..2 edges, in slots A then B)
  if (k < p1)     edge_compute(bf4_to_f32(xA), a0A, a1A, rsumA, accA);
  if (k + 1 < p1) edge_compute(bf4_to_f32(xB), a0B, a1B, rsumB, accB);

  // self loop with precomputed mean edge_attr
  f32x4 em0 = *(const f32x4*)(const void*)&ea_mean[(long)node * 8];
  f32x4 em1 = *(const f32x4*)(const void*)&ea_mean[(long)node * 8 + 4];
  f32x4 xls_self = bf4_to_f32(*(const short4v*)(const void*)&xlb[(long)node * HC + cbase]);
  edge_compute(xls_self, em0, em1, rsumB, accB);

  float invs = 1.f / (rsumA + rsumB);
  f32x4 biasv = *(const f32x4*)(const void*)&bias[cbase];
  short4v pk;
#pragma unroll
  for (int r = 0; r < 4; ++r) {
    float v = fmaxf((accA[r] + accB[r]) * invs + biasv[r], 0.f);
    __hip_bfloat16 hv = __float2bfloat16(v);
    pk[r] = *(short*)&hv;
  }
  *(short4v*)&out[(long)node * HC + cbase] = pk;
}

extern "C" void kernel_launch(void* const* d_in, const int* in_sizes, int n_in,
                              void* d_out, int out_size, void* d_ws, size_t ws_size,
                              hipStream_t stream)
{
  const float* x          = (const float*)d_in[0];
  const int*   edge_index = (const int*)d_in[1];
  const float* edge_attr  = (const float*)d_in[2];
  const float* fp         = (const float*)d_in[4];
  const float* desc       = (const float*)d_in[5];
  const float *c1_Wl = (const float*)d_in[6],  *c1_bl = (const float*)d_in[7],
              *c1_Wr = (const float*)d_in[8],  *c1_br = (const float*)d_in[9],
              *c1_We = (const float*)d_in[10], *c1_att = (const float*)d_in[11],
              *c1_bias = (const float*)d_in[12];
  const float *c2_Wl = (const float*)d_in[13], *c2_bl = (const float*)d_in[14],
              *c2_Wr = (const float*)d_in[15], *c2_br = (const float*)d_in[16],
              *c2_We = (const float*)d_in[17], *c2_att = (const float*)d_in[18],
              *c2_bias = (const float*)d_in[19];
  const float *gW = (const float*)d_in[20], *gb = (const float*)d_in[21],
              *g_gn = (const float*)d_in[22], *g_bt = (const float*)d_in[23];
  const float *fW = (const float*)d_in[24], *fb = (const float*)d_in[25],
              *f_gn = (const float*)d_in[26], *f_bt = (const float*)d_in[27];
  const float *dW = (const float*)d_in[28], *db = (const float*)d_in[29],
              *d_gn = (const float*)d_in[30], *d_bt = (const float*)d_in[31];
  const float *k1W = (const float*)d_in[32], *k1b = (const float*)d_in[33],
              *k1_gn = (const float*)d_in[34], *k1_bt = (const float*)d_in[35];
  const float *k2W = (const float*)d_in[36], *k2b = (const float*)d_in[37],
              *k2_gn = (const float*)d_in[38], *k2_bt = (const float*)d_in[39];
  const float *k3W = (const float*)d_in[40], *k3b = (const float*)d_in[41];

  const int N = in_sizes[0] / 32;       // 32768
  const int E = in_sizes[1] / 2;        // 262144
  const int G = in_sizes[4] / 2048;     // 1024
  const int FIN = 32, FPIN = 2048;
  const int DIN = in_sizes[5] / G;      // 200

  char* ws = (char*)d_ws;
  size_t off = 0;
  auto alloc = [&](size_t bytes) {
    void* p = ws + off;
    off = (off + bytes + 255) & ~(size_t)255;
    return p;
  };
  __hip_bfloat16* xlb    = (__hip_bfloat16*)alloc((size_t)N * HC * 2);  // 16 MB
  __hip_bfloat16* xrb    = (__hip_bfloat16*)alloc((size_t)N * HC * 2);  // 16 MB
  __hip_bfloat16* hb1    = (__hip_bfloat16*)alloc((size_t)N * HC * 2);  // 16 MB
  __hip_bfloat16* hb2    = (__hip_bfloat16*)alloc((size_t)N * HC * 2);  // 16 MB
  __hip_bfloat16* xbf    = (__hip_bfloat16*)alloc((size_t)N * FIN * 2);
  __hip_bfloat16* fpbf   = (__hip_bfloat16*)alloc((size_t)G * FPIN * 2); // 4 MB
  __hip_bfloat16* wt1    = (__hip_bfloat16*)alloc((size_t)512 * FIN * 2);
  __hip_bfloat16* wt2    = (__hip_bfloat16*)alloc((size_t)512 * HC * 2);
  __hip_bfloat16* fwt    = (__hip_bfloat16*)alloc((size_t)256 * FPIN * 2); // 1 MB
  __hip_bfloat16* descbf = (__hip_bfloat16*)alloc((size_t)G * 224 * 2);
  __hip_bfloat16* dwt    = (__hip_bfloat16*)alloc((size_t)64 * 224 * 2);
  __hip_bfloat16* k1wt   = (__hip_bfloat16*)alloc((size_t)384 * 192 * 2);
  __hip_bfloat16* zbuf   = (__hip_bfloat16*)alloc((size_t)G * 384 * 2);
  float* P_fp    = (float*)alloc((size_t)4 * G * 256 * 4);             // 4 MB
  int*   deg     = (int*)alloc((size_t)N * 4);
  int*   csr_ptr = (int*)alloc((size_t)(N + 1) * 4);
  int*   cursor  = (int*)alloc((size_t)N * 4);
  int*   csr_src = (int*)alloc((size_t)E * 4);
  float* csr_ea  = (float*)alloc((size_t)E * 8 * 4);                  // 8 MB
  float* ea_mean = (float*)alloc((size_t)N * 8 * 4);                  // 1 MB
  (void)ws_size;

  const int* srcp = edge_index;
  const int* dstp = edge_index + E;

  hipMemsetAsync(deg, 0, (size_t)N * 4, stream);

  // prep: vectorized conversions + transposes + k1wt + fwt + degree count
  {
    long total = (long)N * 8 + (long)G * 512 + 512 * 32 + 512 * 256 +
                 (long)G * 224 + 64 * 224 + 384 * 192 + 256 * 2048 + E;
    prep_kernel<<<(int)((total + 255) / 256), 256, 0, stream>>>(
        x, fp, c1_Wl, c1_Wr, c2_Wl, c2_Wr, desc, dW, k1W, fW, dstp, deg,
        xbf, fpbf, wt1, wt2, descbf, dwt, k1wt, fwt, N, G, E, DIN);
  }
  // fused single-block CSR scan (replaces scan1+scan2)
  scan_kernel<<<1, 1024, 0, stream>>>(deg, csr_ptr, cursor, N);

  // MEGA1: CSR fill ∪ layer-1 GEMM ∪ fp split-K GEMM ∪ desc GEMM
  {
    int nblk = E / 256 + (N / 128) * 4 + (G / 64) * 16 + G / 64; // 1024+1024+256+16
    mega1_kernel<<<nblk, 256, 0, stream>>>(
        srcp, dstp, edge_attr, cursor, csr_src, csr_ea,
        xbf, wt1, c1_bl, c1_br, xlb, xrb,
        fpbf, fwt, P_fp, descbf, dwt, db, d_gn, d_bt, zbuf, N, G, E);
  }

  // MEGA2: ea_mean ∪ fp epilogue (deps: mega1)
  mega2_kernel<<<N * 8 / 256 + G, 256, 0, stream>>>(
      csr_ea, csr_ptr, ea_mean, P_fp, fb, f_gn, f_bt, zbuf, N, G);

  // layer 1 aggregation
  gat_kernel<<<N / 2, 128, 0, stream>>>(xlb, xrb, csr_ea, csr_src, csr_ptr, ea_mean,
                                        c1_We, c1_att, c1_bias, hb1, N);
  // layer 2
  gemm_mfma_kernel<<<dim3(N / 128, 4), 256, 0, stream>>>(hb1, wt2, c2_bl, c2_br, xlb, xrb, N, HC);
  gat_kernel<<<N / 2, 128, 0, stream>>>(xlb, xrb, csr_ea, csr_src, csr_ptr, ea_mean,
                                        c2_We, c2_att, c2_bias, hb2, N);

  // fused pool + g branch -> zbuf[:,0:64]
  poolg_kernel<<<G, 256, 0, stream>>>(hb2, gW, gb, g_gn, g_bt, zbuf, N / G);

  // fused k1+k2+k3 head -> d_out
  head123_kernel<<<G / 8, 256, 0, stream>>>(zbuf, k1wt, k1b, k1_gn, k1_bt,
                                            k2W, k2b, k2_gn, k2_bt,
                                            k3W, k3b, (float*)d_out);
}

// Round 11
// 377.961 us; speedup vs baseline: 1.1026x; 1.1026x over previous
//
#include <hip/hip_runtime.h>
#include <hip/hip_bf16.h>
#include <math.h>

#define NHEAD 4
#define HC 256

typedef short short8 __attribute__((ext_vector_type(8)));
typedef short short4v __attribute__((ext_vector_type(4)));
typedef float f32x4 __attribute__((ext_vector_type(4)));

__device__ inline f32x4 bf4_to_f32(short4v v)
{
  f32x4 r;
#pragma unroll
  for (int i = 0; i < 4; ++i)
    r[i] = __uint_as_float(((unsigned)(unsigned short)v[i]) << 16);
  return r;
}

__device__ inline float bf_to_f32(unsigned short u)
{
  return __uint_as_float(((unsigned)u) << 16);
}

__device__ inline short4v f4_to_bf4(f32x4 v)
{
  short4v o;
#pragma unroll
  for (int i = 0; i < 4; ++i) {
    __hip_bfloat16 h = __float2bfloat16(v[i]);
    o[i] = *(short*)&h;
  }
  return o;
}

// DPP rotate-add within a row of 16 lanes (VALU-only).
template <int CTRL>
__device__ inline float dpp_radd(float x)
{
  int yi = __builtin_amdgcn_update_dpp(0, __float_as_int(x), CTRL, 0xf, 0xf, true);
  return x + __int_as_float(yi);
}

// ------- one fused prep kernel -------
// R20: x/fp conversions vectorized; fwt transpose folded in.
// R24: exact R9 restoration — R10's single-block scan (+~30us, 1-CU
// wave-uncoalesced strip loads) and head123 reverted. One-change discipline.
__global__ void prep_kernel(
    const float* __restrict__ x, const float* __restrict__ fp,
    const float* __restrict__ c1Wl, const float* __restrict__ c1Wr,
    const float* __restrict__ c2Wl, const float* __restrict__ c2Wr,
    const float* __restrict__ desc, const float* __restrict__ dW,
    const float* __restrict__ k1W, const float* __restrict__ fW,
    const int* __restrict__ dst, int* __restrict__ deg,
    __hip_bfloat16* __restrict__ xbf, __hip_bfloat16* __restrict__ fpbf,
    __hip_bfloat16* __restrict__ wt1, __hip_bfloat16* __restrict__ wt2,
    __hip_bfloat16* __restrict__ descbf, __hip_bfloat16* __restrict__ dwt,
    __hip_bfloat16* __restrict__ k1wt, __hip_bfloat16* __restrict__ fwt,
    int N, int G, int E, int DIN)
{
  const int n0 = N * 8;       // x as vec4 (N*32/4)
  const int n1 = G * 512;     // fp as vec4 (G*2048/4)
  const int n2 = 512 * 32, n3 = 512 * 256;
  const int n4 = G * 224, n5 = 64 * 224, n6 = 192 * 384;
  const int n7 = 256 * 2048; // fwt transpose
  int idx = blockIdx.x * 256 + threadIdx.x;
  if (idx < n0) {
    f32x4 v = ((const f32x4*)x)[idx];
    ((short4v*)xbf)[idx] = f4_to_bf4(v);
    return;
  }
  idx -= n0;
  if (idx < n1) {
    f32x4 v = ((const f32x4*)fp)[idx];
    ((short4v*)fpbf)[idx] = f4_to_bf4(v);
    return;
  }
  idx -= n1;
  if (idx < n2) {
    int n = idx / 32, k = idx - n * 32;
    float v = (n < 256) ? c1Wl[k * 256 + n] : c1Wr[k * 256 + (n - 256)];
    wt1[idx] = __float2bfloat16(v); return;
  }
  idx -= n2;
  if (idx < n3) {
    int n = idx / 256, k = idx - n * 256;
    float v = (n < 256) ? c2Wl[k * 256 + n] : c2Wr[k * 256 + (n - 256)];
    wt2[idx] = __float2bfloat16(v); return;
  }
  idx -= n3;
  if (idx < n4) {
    int row = idx / 224, kp = idx - row * 224;
    float v = (kp < DIN) ? desc[(long)row * DIN + kp] : 0.f;
    descbf[idx] = __float2bfloat16(v); return;
  }
  idx -= n4;
  if (idx < n5) {
    int n = idx / 224, kp = idx - n * 224;
    float v = (kp < DIN) ? dW[kp * 64 + n] : 0.f;
    dwt[idx] = __float2bfloat16(v); return;
  }
  idx -= n5;
  if (idx < n6) {
    int n = idx / 384, k = idx - n * 384;
    k1wt[idx] = __float2bfloat16(k1W[k * 192 + n]); return;
  }
  idx -= n6;
  if (idx < n7) {
    int n = idx >> 11, k = idx & 2047;   // fwt[n][k] = fW[k][n]
    fwt[idx] = __float2bfloat16(fW[k * 256 + n]); return;
  }
  idx -= n7;
  if (idx < E) atomicAdd(&deg[dst[idx]], 1);
}

// ------- bf16 MFMA GEMM: [xl|xr] = A[M][K] @ W[K][512] + bias -> bf16 tables
// (used standalone for layer 2; layer 1 is folded into mega1)
__global__ __launch_bounds__(256) void gemm_mfma_kernel(
    const __hip_bfloat16* __restrict__ A, const __hip_bfloat16* __restrict__ BT,
    const float* __restrict__ bl, const float* __restrict__ br,
    __hip_bfloat16* __restrict__ XL, __hip_bfloat16* __restrict__ XR, int M, int K)
{
  __shared__ short As[128 * 40];
  __shared__ short Bs[128 * 40];
  int bm = blockIdx.x * 128, bn = blockIdx.y * 128;
  int t = threadIdx.x;
  int w = t >> 6, l = t & 63;
  int quad = l >> 4, l16 = l & 15;
  int srow = t >> 1, scol = (t & 1) * 16;

  f32x4 acc[2][8];
#pragma unroll
  for (int i = 0; i < 2; ++i)
#pragma unroll
    for (int j = 0; j < 8; ++j) acc[i][j] = (f32x4){0.f, 0.f, 0.f, 0.f};

  for (int k0 = 0; k0 < K; k0 += 32) {
    *(short8*)&As[srow * 40 + scol] =
        *(const short8*)(const void*)&A[(long)(bm + srow) * K + k0 + scol];
    *(short8*)&As[srow * 40 + scol + 8] =
        *(const short8*)(const void*)&A[(long)(bm + srow) * K + k0 + scol + 8];
    *(short8*)&Bs[srow * 40 + scol] =
        *(const short8*)(const void*)&BT[(long)(bn + srow) * K + k0 + scol];
    *(short8*)&Bs[srow * 40 + scol + 8] =
        *(const short8*)(const void*)&BT[(long)(bn + srow) * K + k0 + scol + 8];
    __syncthreads();
    short8 af[2], bf[8];
#pragma unroll
    for (int mt = 0; mt < 2; ++mt)
      af[mt] = *(short8*)&As[(w * 32 + mt * 16 + l16) * 40 + quad * 8];
#pragma unroll
    for (int nt = 0; nt < 8; ++nt)
      bf[nt] = *(short8*)&Bs[(nt * 16 + l16) * 40 + quad * 8];
#pragma unroll
    for (int mt = 0; mt < 2; ++mt)
#pragma unroll
      for (int nt = 0; nt < 8; ++nt)
        acc[mt][nt] = __builtin_amdgcn_mfma_f32_16x16x32_bf16(af[mt], bf[nt], acc[mt][nt], 0, 0, 0);
    __syncthreads();
  }
#pragma unroll
  for (int mt = 0; mt < 2; ++mt)
#pragma unroll
    for (int nt = 0; nt < 8; ++nt) {
      int col = bn + nt * 16 + l16;
      float b = (col < 256) ? bl[col] : br[col - 256];
#pragma unroll
      for (int r = 0; r < 4; ++r) {
        int row = bm + w * 32 + mt * 16 + quad * 4 + r;
        float v = acc[mt][nt][r] + b;
        if (col < 256)
          XL[(long)row * 256 + col] = __float2bfloat16(v);
        else
          XR[(long)row * 256 + (col - 256)] = __float2bfloat16(v);
      }
    }
}

// ------- bf16 MFMA GEMM + relu + bn epilogue; out bf16 (obf=1) or fp32 -------
__global__ __launch_bounds__(256) void gemm_rb_kernel(
    const __hip_bfloat16* __restrict__ A, const __hip_bfloat16* __restrict__ BT,
    const float* __restrict__ bias, const float* __restrict__ gamma,
    const float* __restrict__ beta, void* __restrict__ out,
    int M, int K, int ldc, int coloff, int obf)
{
  __shared__ short As[64 * 40];
  __shared__ short Bs[64 * 40];
  int bm = blockIdx.x * 64, bn = blockIdx.y * 64;
  int t = threadIdx.x;
  int w = t >> 6, l = t & 63;
  int quad = l >> 4, l16 = l & 15;
  int lrow = t >> 2, col8 = (t & 3) * 8;

  f32x4 acc[4];
#pragma unroll
  for (int nt = 0; nt < 4; ++nt) acc[nt] = (f32x4){0.f, 0.f, 0.f, 0.f};

  for (int k0 = 0; k0 < K; k0 += 32) {
    *(short8*)&As[lrow * 40 + col8] =
        *(const short8*)(const void*)&A[(long)(bm + lrow) * K + k0 + col8];
    *(short8*)&Bs[lrow * 40 + col8] =
        *(const short8*)(const void*)&BT[(long)(bn + lrow) * K + k0 + col8];
    __syncthreads();
    short8 af = *(short8*)&As[(w * 16 + l16) * 40 + quad * 8];
#pragma unroll
    for (int nt = 0; nt < 4; ++nt) {
      short8 bf = *(short8*)&Bs[(nt * 16 + l16) * 40 + quad * 8];
      acc[nt] = __builtin_amdgcn_mfma_f32_16x16x32_bf16(af, bf, acc[nt], 0, 0, 0);
    }
    __syncthreads();
  }
  const float inv = rsqrtf(1.f + 1e-5f);
#pragma unroll
  for (int nt = 0; nt < 4; ++nt) {
    int col = bn + nt * 16 + l16;
    float b = bias[col], gm = gamma[col] * inv, bt = beta[col];
#pragma unroll
    for (int r = 0; r < 4; ++r) {
      int row = bm + w * 16 + quad * 4 + r;
      float v = fmaxf(acc[nt][r] + b, 0.f) * gm + bt;
      if (obf)
        ((__hip_bfloat16*)out)[(long)row * ldc + coloff + col] = __float2bfloat16(v);
      else
        ((float*)out)[(long)row * ldc + coloff + col] = v;
    }
  }
}

// ------- MEGA1: CSR fill ∪ layer-1 transform GEMM ∪ fp split-K GEMM ∪ desc
// GEMM. All depend only on prep+scan2. One dispatch: fill's scatter/atomic
// latency hides under the MFMA compute of the other ranges (R21). -----
__global__ __launch_bounds__(256) void mega1_kernel(
    const int* __restrict__ esrc, const int* __restrict__ edst,
    const float* __restrict__ ea, int* __restrict__ cursor,
    int* __restrict__ csr_src, float* __restrict__ csr_ea,
    const __hip_bfloat16* __restrict__ xbf, const __hip_bfloat16* __restrict__ wt1,
    const float* __restrict__ c1_bl, const float* __restrict__ c1_br,
    __hip_bfloat16* __restrict__ xlb, __hip_bfloat16* __restrict__ xrb,
    const __hip_bfloat16* __restrict__ fpbf, const __hip_bfloat16* __restrict__ fwt,
    float* __restrict__ P,
    const __hip_bfloat16* __restrict__ descbf, const __hip_bfloat16* __restrict__ dwt,
    const float* __restrict__ db, const float* __restrict__ d_gn,
    const float* __restrict__ d_bt, __hip_bfloat16* __restrict__ zbuf,
    int N, int G, int E)
{
  __shared__ short As[128 * 40];
  __shared__ short Bs[128 * 40];
  int b = blockIdx.x;
  const int t = threadIdx.x;
  const int NB_FILL = E / 256;          // 1024
  const int GX1 = N / 128;              // 256
  const int NB_GEMM1 = GX1 * 4;         // 1024
  const int NB_SKB = (G / 64) * 16;     // 256

  if (b < NB_FILL) {
    // ---- CSR fill: scatter src + edge_attr ----
    int e = b * 256 + t;
    if (e < E) {
      int pos = atomicAdd(&cursor[edst[e]], 1);
      csr_src[pos] = esrc[e];
      f32x4 a0 = *(const f32x4*)(const void*)&ea[(long)e * 8];
      f32x4 a1 = *(const f32x4*)(const void*)&ea[(long)e * 8 + 4];
      *(f32x4*)&csr_ea[(long)pos * 8] = a0;
      *(f32x4*)&csr_ea[(long)pos * 8 + 4] = a1;
    }
    return;
  }
  b -= NB_FILL;
  if (b < NB_GEMM1) {
    // ---- layer-1 transform GEMM: [xl|xr] = xbf @ wt1 + bias, K=32 ----
    int bx = b % GX1, by = b / GX1;
    int bm = bx * 128, bn = by * 128;
    const int K = 32;
    int w = t >> 6, l = t & 63;
    int quad = l >> 4, l16 = l & 15;
    int srow = t >> 1, scol = (t & 1) * 16;

    f32x4 acc[2][8];
#pragma unroll
    for (int i = 0; i < 2; ++i)
#pragma unroll
      for (int j = 0; j < 8; ++j) acc[i][j] = (f32x4){0.f, 0.f, 0.f, 0.f};

    {
      const int k0 = 0;
      *(short8*)&As[srow * 40 + scol] =
          *(const short8*)(const void*)&xbf[(long)(bm + srow) * K + k0 + scol];
      *(short8*)&As[srow * 40 + scol + 8] =
          *(const short8*)(const void*)&xbf[(long)(bm + srow) * K + k0 + scol + 8];
      *(short8*)&Bs[srow * 40 + scol] =
          *(const short8*)(const void*)&wt1[(long)(bn + srow) * K + k0 + scol];
      *(short8*)&Bs[srow * 40 + scol + 8] =
          *(const short8*)(const void*)&wt1[(long)(bn + srow) * K + k0 + scol + 8];
      __syncthreads();
      short8 af[2], bf[8];
#pragma unroll
      for (int mt = 0; mt < 2; ++mt)
        af[mt] = *(short8*)&As[(w * 32 + mt * 16 + l16) * 40 + quad * 8];
#pragma unroll
      for (int nt = 0; nt < 8; ++nt)
        bf[nt] = *(short8*)&Bs[(nt * 16 + l16) * 40 + quad * 8];
#pragma unroll
      for (int mt = 0; mt < 2; ++mt)
#pragma unroll
        for (int nt = 0; nt < 8; ++nt)
          acc[mt][nt] = __builtin_amdgcn_mfma_f32_16x16x32_bf16(af[mt], bf[nt], acc[mt][nt], 0, 0, 0);
    }
#pragma unroll
    for (int mt = 0; mt < 2; ++mt)
#pragma unroll
      for (int nt = 0; nt < 8; ++nt) {
        int col = bn + nt * 16 + l16;
        float bb = (col < 256) ? c1_bl[col] : c1_br[col - 256];
#pragma unroll
        for (int r = 0; r < 4; ++r) {
          int row = bm + w * 32 + mt * 16 + quad * 4 + r;
          float v = acc[mt][nt][r] + bb;
          if (col < 256)
            xlb[(long)row * 256 + col] = __float2bfloat16(v);
          else
            xrb[(long)row * 256 + (col - 256)] = __float2bfloat16(v);
        }
      }
    return;
  }
  b -= NB_GEMM1;
  if (b < NB_SKB) {
    // ---- fp branch split-K GEMM: P[s] = fpbf @ fwt (K-slice) ----
    const int gx = G / 64;
    int bx = b % gx, rem = b / gx;
    int by = rem & 3, s = rem >> 2;
    int bm = bx * 64, bn = by * 64;
    const int K = 2048, Kc = 512;
    int kb = s * Kc, ke = kb + Kc;
    int w = t >> 6, l = t & 63;
    int quad = l >> 4, l16 = l & 15;
    int lrow = t >> 2, col8 = (t & 3) * 8;

    f32x4 acc[4];
#pragma unroll
    for (int nt = 0; nt < 4; ++nt) acc[nt] = (f32x4){0.f, 0.f, 0.f, 0.f};

    for (int k0 = kb; k0 < ke; k0 += 32) {
      *(short8*)&As[lrow * 40 + col8] =
          *(const short8*)(const void*)&fpbf[(long)(bm + lrow) * K + k0 + col8];
      *(short8*)&Bs[lrow * 40 + col8] =
          *(const short8*)(const void*)&fwt[(long)(bn + lrow) * K + k0 + col8];
      __syncthreads();
      short8 af = *(short8*)&As[(w * 16 + l16) * 40 + quad * 8];
#pragma unroll
      for (int nt = 0; nt < 4; ++nt) {
        short8 bf = *(short8*)&Bs[(nt * 16 + l16) * 40 + quad * 8];
        acc[nt] = __builtin_amdgcn_mfma_f32_16x16x32_bf16(af, bf, acc[nt], 0, 0, 0);
      }
      __syncthreads();
    }
#pragma unroll
    for (int nt = 0; nt < 4; ++nt) {
      int col = bn + nt * 16 + l16;
#pragma unroll
      for (int r = 0; r < 4; ++r) {
        int row = bm + w * 16 + quad * 4 + r;
        P[((long)s * G + row) * 256 + col] = acc[nt][r];
      }
    }
    return;
  }
  b -= NB_SKB;
  {
    // ---- desc branch GEMM + relu + bn -> zbuf[:,320:384] bf16 ----
    int bm = b * 64;
    const int K = 224;
    int w = t >> 6, l = t & 63;
    int quad = l >> 4, l16 = l & 15;
    int lrow = t >> 2, col8 = (t & 3) * 8;

    f32x4 acc[4];
#pragma unroll
    for (int nt = 0; nt < 4; ++nt) acc[nt] = (f32x4){0.f, 0.f, 0.f, 0.f};

    for (int k0 = 0; k0 < K; k0 += 32) {
      *(short8*)&As[lrow * 40 + col8] =
          *(const short8*)(const void*)&descbf[(long)(bm + lrow) * K + k0 + col8];
      *(short8*)&Bs[lrow * 40 + col8] =
          *(const short8*)(const void*)&dwt[(long)lrow * K + k0 + col8];
      __syncthreads();
      short8 af = *(short8*)&As[(w * 16 + l16) * 40 + quad * 8];
#pragma unroll
      for (int nt = 0; nt < 4; ++nt) {
        short8 bf = *(short8*)&Bs[(nt * 16 + l16) * 40 + quad * 8];
        acc[nt] = __builtin_amdgcn_mfma_f32_16x16x32_bf16(af, bf, acc[nt], 0, 0, 0);
      }
      __syncthreads();
    }
    const float inv = rsqrtf(1.f + 1e-5f);
#pragma unroll
    for (int nt = 0; nt < 4; ++nt) {
      int col = nt * 16 + l16;   // bn = 0, 64 cols
      float bb = db[col], gm = d_gn[col] * inv, bt = d_bt[col];
#pragma unroll
      for (int r = 0; r < 4; ++r) {
        int row = bm + w * 16 + quad * 4 + r;
        float v = fmaxf(acc[nt][r] + bb, 0.f) * gm + bt;
        zbuf[(long)row * 384 + 320 + col] = __float2bfloat16(v);
      }
    }
  }
}

// ------- MEGA2: eamean (gather-latency) ∪ fp split-K epilogue (streaming) ---
__global__ __launch_bounds__(256) void mega2_kernel(
    const float* __restrict__ csr_ea, const int* __restrict__ csr_ptr,
    float* __restrict__ ea_mean,
    const float* __restrict__ P, const float* __restrict__ fb,
    const float* __restrict__ f_gn, const float* __restrict__ f_bt,
    __hip_bfloat16* __restrict__ zbuf, int N, int G)
{
  int b = blockIdx.x;
  int t = threadIdx.x;
  const int NB_EA = N * 8 / 256;   // 1024
  if (b < NB_EA) {
    int idx = b * 256 + t;
    int node = idx >> 3, d = idx & 7;
    int p0 = csr_ptr[node], p1 = csr_ptr[node + 1];
    float s = 0.f;
    for (int k = p0; k < p1; ++k) s += csr_ea[(long)k * 8 + d];
    int cnt = p1 - p0;
    ea_mean[idx] = s / (float)(cnt > 1 ? cnt : 1);
    return;
  }
  b -= NB_EA;
  int idx = b * 256 + t;           // over G*256
  int row = idx >> 8, col = idx & 255;
  float v = 0.f;
#pragma unroll
  for (int s = 0; s < 4; ++s) v += P[(long)s * G * 256 + idx];
  const float inv = rsqrtf(1.f + 1e-5f);
  v = fmaxf(v + fb[col], 0.f) * (f_gn[col] * inv) + f_bt[col];
  zbuf[(long)row * 384 + 64 + col] = __float2bfloat16(v);
}

// -------- fused pool + g branch: per-graph colmax (LDS) -> 64-col dense -----
__global__ __launch_bounds__(256) void poolg_kernel(
    const __hip_bfloat16* __restrict__ h, const float* __restrict__ gW,
    const float* __restrict__ gb, const float* __restrict__ g_gn,
    const float* __restrict__ g_bt, __hip_bfloat16* __restrict__ zbuf, int npg)
{
  __shared__ float smax[256];
  __shared__ float sred[256];
  int g = blockIdx.x, t = threadIdx.x;
  const __hip_bfloat16* base = h + (long)g * npg * HC + t;
  float m = -INFINITY;
#pragma unroll 4
  for (int i = 0; i < npg; ++i)
    m = fmaxf(m, bf_to_f32(*(const unsigned short*)&base[(long)i * HC]));
  smax[t] = m;
  __syncthreads();
  int j = t >> 2, part = t & 3;
  float sum = 0.f;
#pragma unroll 4
  for (int k = part * 64; k < part * 64 + 64; ++k)
    sum = fmaf(smax[k], gW[k * 64 + j], sum);
  sred[t] = sum;
  __syncthreads();
  if (t < 64) {
    float v = sred[t * 4] + sred[t * 4 + 1] + sred[t * 4 + 2] + sred[t * 4 + 3];
    const float inv = rsqrtf(1.f + 1e-5f);
    v = fmaxf(v + gb[t], 0.f) * (g_gn[t] * inv) + g_bt[t];
    zbuf[(long)g * 384 + t] = __float2bfloat16(v);
  }
}

// -------- fused k2+k3 head: z1(fp32) -> d_out --------
// R15: k2W staged in LDS in two 96-row K-halves; all inner-loop operands LDS.
__global__ __launch_bounds__(256) void head23_kernel(
    const float* __restrict__ z1, const float* __restrict__ k2W,
    const float* __restrict__ k2b, const float* __restrict__ k2_gn,
    const float* __restrict__ k2_bt, const float* __restrict__ k3W,
    const float* __restrict__ k3b, float* __restrict__ out)
{
  __shared__ float sW[96 * 96];    // K-half tile of k2W (36.9 KB)
  __shared__ float s1[8 * 192];    // 6 KB
  __shared__ float s2[8 * 96];     // 3 KB
  __shared__ float sk3[96 * 12];   // 4.6 KB
  int b = blockIdx.x, t = threadIdx.x;

  for (int i = t; i < 8 * 192; i += 256) s1[i] = z1[(long)b * (8 * 192) + i];
  for (int i = t; i < 96 * 12; i += 256) sk3[i] = k3W[i];

  // outputs: idx = o*256 + t, o<3 -> 768 = 8 rows x 96 cols
  int row[3], col[3];
  float acc[3] = {0.f, 0.f, 0.f};
#pragma unroll
  for (int o = 0; o < 3; ++o) {
    int idx = o * 256 + t;
    row[o] = idx / 96;
    col[o] = idx - row[o] * 96;
  }

  for (int half = 0; half < 2; ++half) {
    __syncthreads();  // previous-half compute done before overwriting sW
    for (int i = t; i < 96 * 96; i += 256)
      sW[i] = k2W[(long)half * 96 * 96 + i];
    __syncthreads();
#pragma unroll 4
    for (int k = 0; k < 96; ++k) {
#pragma unroll
      for (int o = 0; o < 3; ++o)
        acc[o] = fmaf(s1[row[o] * 192 + half * 96 + k], sW[k * 96 + col[o]], acc[o]);
    }
  }

  const float inv = rsqrtf(1.f + 1e-5f);
#pragma unroll
  for (int o = 0; o < 3; ++o) {
    float v = fmaxf(acc[o] + k2b[col[o]], 0.f) * (k2_gn[col[o]] * inv) + k2_bt[col[o]];
    s2[o * 256 + t] = v;
  }
  __syncthreads();
  if (t < 96) {
    int r3 = t / 12, c3 = t - r3 * 12;
    float a = 0.f;
#pragma unroll 4
    for (int k = 0; k < 96; ++k) a = fmaf(s2[r3 * 96 + k], sk3[k * 12 + c3], a);
    out[(long)(b * 8 + r3) * 12 + c3] = a + k3b[c3];
  }
}

// ---------------- CSR build: 2-pass coalesced scan ----------------
// pass 1: block-local exclusive scan of deg (1024/block), block totals -> bsum
__global__ __launch_bounds__(1024) void scan1_kernel(
    const int* __restrict__ deg, int* __restrict__ ptr,
    int* __restrict__ bsum, int N)
{
  __shared__ int s[1024];
  int b = blockIdx.x, t = threadIdx.x;
  int i = b * 1024 + t;
  int v = (i < N) ? deg[i] : 0;
  s[t] = v;
  __syncthreads();
  for (int off = 1; off < 1024; off <<= 1) {
    int x = (t >= off) ? s[t - off] : 0;
    __syncthreads();
    s[t] += x;
    __syncthreads();
  }
  if (i < N) ptr[i] = s[t] - v;   // local exclusive prefix
  if (t == 1023) bsum[b] = s[1023];
}

// pass 2: add block offsets; write cursor and ptr[N]
__global__ __launch_bounds__(256) void scan2_kernel(
    const int* __restrict__ bsum, int* __restrict__ ptr,
    int* __restrict__ cursor, int N, int nb)
{
  int i = blockIdx.x * 256 + threadIdx.x;
  if (i > N) return;
  if (i == N) {
    int tot = 0;
    for (int j = 0; j < nb; ++j) tot += bsum[j];
    ptr[N] = tot;
    return;
  }
  int b = i >> 10;
  int offv = 0;
  for (int j = 0; j < b; ++j) offv += bsum[j];
  int v = ptr[i] + offv;
  ptr[i] = v;
  cursor[i] = v;
}

// ---------------- GATv2 aggregation ----------------
// FROZEN since R19: byte-for-byte the R1 version — the measured optimum
// across R1-R5 (61.2us, VGPR=64). Lessons: (a) must sit at VGPR<=64 (m69
// cliff), allocator lands there naturally ONLY with this structure; (b)
// never min-waves launch_bounds here; (c) occupancy is dispatch-limited at
// ~2.8 waves/SIMD regardless of geometry.
__global__ __launch_bounds__(128) void gat_kernel(
    const __hip_bfloat16* __restrict__ xlb, const __hip_bfloat16* __restrict__ xrb,
    const float* __restrict__ csr_ea, const int* __restrict__ csr_src,
    const int* __restrict__ csr_ptr, const float* __restrict__ ea_mean,
    const float* __restrict__ We, const float* __restrict__ att,
    const float* __restrict__ bias, __hip_bfloat16* __restrict__ out, int N)
{
  int lane = threadIdx.x & 63;
  int node = blockIdx.x * 2 + (threadIdx.x >> 6);
  if (node >= N) return;
  int cbase = (lane >> 4) * 64 + (lane & 15) * 4;  // channel offset in [0,256)

  f32x4 attv = *(const f32x4*)(const void*)&att[cbase];
  f32x4 xriv = bf4_to_f32(*(const short4v*)(const void*)&xrb[(long)node * HC + cbase]);
  f32x4 WeR[8];
#pragma unroll
  for (int d = 0; d < 8; ++d)
    WeR[d] = *(const f32x4*)(const void*)&We[d * HC + cbase];

  float rsumA = 0.f, rsumB = 0.f;
  f32x4 accA = (f32x4){0.f, 0.f, 0.f, 0.f};
  f32x4 accB = (f32x4){0.f, 0.f, 0.f, 0.f};

  int p0 = csr_ptr[node], p1 = csr_ptr[node + 1];

  auto edge_compute = [&](f32x4 xls, f32x4 ea0, f32x4 ea1,
                          float& rsum, f32x4& acc) {
    f32x4 mv = xriv + xls;
#pragma unroll
    for (int d = 0; d < 4; ++d) mv += WeR[d] * ea0[d];
#pragma unroll
    for (int d = 0; d < 4; ++d) mv += WeR[d + 4] * ea1[d];
    float t = 0.f;
#pragma unroll
    for (int r = 0; r < 4; ++r) {
      float m = mv[r];
      m = (m > 0.f) ? m : 0.2f * m;
      t = fmaf(m, attv[r], t);
    }
    t = dpp_radd<0x121>(t);
    t = dpp_radd<0x122>(t);
    t = dpp_radd<0x124>(t);
    t = dpp_radd<0x128>(t);
    float p = __expf(t);
    rsum += p;
    acc += p * xls;
  };

  // data slots A/B/C hold edge k,k+1,k+2 payloads; s3A/s3B/s3C hold src
  // indices for edges k+3,k+4,k+5 (one full group ahead).
  short4v xA = (short4v){0, 0, 0, 0}, xB = xA, xC = xA;
  f32x4 a0A = (f32x4){0.f, 0.f, 0.f, 0.f}, a1A = a0A;
  f32x4 a0B = a0A, a1B = a0A, a0C = a0A, a1C = a0A;
  int s3A = 0, s3B = 0, s3C = 0;

  // prologue: issue all 6 src loads (independent), then ea loads, then the
  // first 3 gathers (these wait once on the first src loads — the only
  // dependent stall per node).
  int s0 = 0, s1 = 0, s2 = 0;
  if (p0 < p1)     s0 = csr_src[p0];
  if (p0 + 1 < p1) s1 = csr_src[p0 + 1];
  if (p0 + 2 < p1) s2 = csr_src[p0 + 2];
  if (p0 + 3 < p1) s3A = csr_src[p0 + 3];
  if (p0 + 4 < p1) s3B = csr_src[p0 + 4];
  if (p0 + 5 < p1) s3C = csr_src[p0 + 5];
  if (p0 < p1) {
    a0A = *(const f32x4*)(const void*)&csr_ea[(long)p0 * 8];
    a1A = *(const f32x4*)(const void*)&csr_ea[(long)p0 * 8 + 4];
    xA = *(const short4v*)(const void*)&xlb[(long)s0 * HC + cbase];
  }
  if (p0 + 1 < p1) {
    a0B = *(const f32x4*)(const void*)&csr_ea[(long)(p0 + 1) * 8];
    a1B = *(const f32x4*)(const void*)&csr_ea[(long)(p0 + 1) * 8 + 4];
    xB = *(const short4v*)(const void*)&xlb[(long)s1 * HC + cbase];
  }
  if (p0 + 2 < p1) {
    a0C = *(const f32x4*)(const void*)&csr_ea[(long)(p0 + 2) * 8];
    a1C = *(const f32x4*)(const void*)&csr_ea[(long)(p0 + 2) * 8 + 4];
    xC = *(const short4v*)(const void*)&xlb[(long)s2 * HC + cbase];
  }

  int k = p0;
  for (; k + 3 <= p1; k += 3) {
    // ---- slot A: edge k; refill edge k+3 (src already in s3A); prefetch
    //      src for edge k+6 into s3A ----
    f32x4 e0 = a0A, e1 = a1A;
    short4v xc = xA;
    if (k + 3 < p1) {
      xA = *(const short4v*)(const void*)&xlb[(long)s3A * HC + cbase];
      a0A = *(const f32x4*)(const void*)&csr_ea[(long)(k + 3) * 8];
      a1A = *(const f32x4*)(const void*)&csr_ea[(long)(k + 3) * 8 + 4];
    }
    if (k + 6 < p1) s3A = csr_src[k + 6];
    edge_compute(bf4_to_f32(xc), e0, e1, rsumA, accA);

    // ---- slot B: edge k+1; refill k+4; src for k+7 ----
    e0 = a0B; e1 = a1B; xc = xB;
    if (k + 4 < p1) {
      xB = *(const short4v*)(const void*)&xlb[(long)s3B * HC + cbase];
      a0B = *(const f32x4*)(const void*)&csr_ea[(long)(k + 4) * 8];
      a1B = *(const f32x4*)(const void*)&csr_ea[(long)(k + 4) * 8 + 4];
    }
    if (k + 7 < p1) s3B = csr_src[k + 7];
    edge_compute(bf4_to_f32(xc), e0, e1, rsumB, accB);

    // ---- slot C: edge k+2; refill k+5; src for k+8 ----
    e0 = a0C; e1 = a1C; xc = xC;
    if (k + 5 < p1) {
      xC = *(const short4v*)(const void*)&xlb[(long)s3C * HC + cbase];
      a0C = *(const f32x4*)(const void*)&csr_ea[(long)(k + 5) * 8];
      a1C = *(const f32x4*)(const void*)&csr_ea[(long)(k + 5) * 8 + 4];
    }
    if (k + 8 < p1) s3C = csr_src[k + 8];
    edge_compute(bf4_to_f32(xc), e0, e1, rsumA, accA);
  }
  // tail (0..2 edges, in slots A then B)
  if (k < p1)     edge_compute(bf4_to_f32(xA), a0A, a1A, rsumA, accA);
  if (k + 1 < p1) edge_compute(bf4_to_f32(xB), a0B, a1B, rsumB, accB);

  // self loop with precomputed mean edge_attr
  f32x4 em0 = *(const f32x4*)(const void*)&ea_mean[(long)node * 8];
  f32x4 em1 = *(const f32x4*)(const void*)&ea_mean[(long)node * 8 + 4];
  f32x4 xls_self = bf4_to_f32(*(const short4v*)(const void*)&xlb[(long)node * HC + cbase]);
  edge_compute(xls_self, em0, em1, rsumB, accB);

  float invs = 1.f / (rsumA + rsumB);
  f32x4 biasv = *(const f32x4*)(const void*)&bias[cbase];
  short4v pk;
#pragma unroll
  for (int r = 0; r < 4; ++r) {
    float v = fmaxf((accA[r] + accB[r]) * invs + biasv[r], 0.f);
    __hip_bfloat16 hv = __float2bfloat16(v);
    pk[r] = *(short*)&hv;
  }
  *(short4v*)&out[(long)node * HC + cbase] = pk;
}

extern "C" void kernel_launch(void* const* d_in, const int* in_sizes, int n_in,
                              void* d_out, int out_size, void* d_ws, size_t ws_size,
                              hipStream_t stream)
{
  const float* x          = (const float*)d_in[0];
  const int*   edge_index = (const int*)d_in[1];
  const float* edge_attr  = (const float*)d_in[2];
  const float* fp         = (const float*)d_in[4];
  const float* desc       = (const float*)d_in[5];
  const float *c1_Wl = (const float*)d_in[6],  *c1_bl = (const float*)d_in[7],
              *c1_Wr = (const float*)d_in[8],  *c1_br = (const float*)d_in[9],
              *c1_We = (const float*)d_in[10], *c1_att = (const float*)d_in[11],
              *c1_bias = (const float*)d_in[12];
  const float *c2_Wl = (const float*)d_in[13], *c2_bl = (const float*)d_in[14],
              *c2_Wr = (const float*)d_in[15], *c2_br = (const float*)d_in[16],
              *c2_We = (const float*)d_in[17], *c2_att = (const float*)d_in[18],
              *c2_bias = (const float*)d_in[19];
  const float *gW = (const float*)d_in[20], *gb = (const float*)d_in[21],
              *g_gn = (const float*)d_in[22], *g_bt = (const float*)d_in[23];
  const float *fW = (const float*)d_in[24], *fb = (const float*)d_in[25],
              *f_gn = (const float*)d_in[26], *f_bt = (const float*)d_in[27];
  const float *dW = (const float*)d_in[28], *db = (const float*)d_in[29],
              *d_gn = (const float*)d_in[30], *d_bt = (const float*)d_in[31];
  const float *k1W = (const float*)d_in[32], *k1b = (const float*)d_in[33],
              *k1_gn = (const float*)d_in[34], *k1_bt = (const float*)d_in[35];
  const float *k2W = (const float*)d_in[36], *k2b = (const float*)d_in[37],
              *k2_gn = (const float*)d_in[38], *k2_bt = (const float*)d_in[39];
  const float *k3W = (const float*)d_in[40], *k3b = (const float*)d_in[41];

  const int N = in_sizes[0] / 32;       // 32768
  const int E = in_sizes[1] / 2;        // 262144
  const int G = in_sizes[4] / 2048;     // 1024
  const int FIN = 32, FPIN = 2048;
  const int DIN = in_sizes[5] / G;      // 200

  char* ws = (char*)d_ws;
  size_t off = 0;
  auto alloc = [&](size_t bytes) {
    void* p = ws + off;
    off = (off + bytes + 255) & ~(size_t)255;
    return p;
  };
  __hip_bfloat16* xlb    = (__hip_bfloat16*)alloc((size_t)N * HC * 2);  // 16 MB
  __hip_bfloat16* xrb    = (__hip_bfloat16*)alloc((size_t)N * HC * 2);  // 16 MB
  __hip_bfloat16* hb1    = (__hip_bfloat16*)alloc((size_t)N * HC * 2);  // 16 MB
  __hip_bfloat16* hb2    = (__hip_bfloat16*)alloc((size_t)N * HC * 2);  // 16 MB
  __hip_bfloat16* xbf    = (__hip_bfloat16*)alloc((size_t)N * FIN * 2);
  __hip_bfloat16* fpbf   = (__hip_bfloat16*)alloc((size_t)G * FPIN * 2); // 4 MB
  __hip_bfloat16* wt1    = (__hip_bfloat16*)alloc((size_t)512 * FIN * 2);
  __hip_bfloat16* wt2    = (__hip_bfloat16*)alloc((size_t)512 * HC * 2);
  __hip_bfloat16* fwt    = (__hip_bfloat16*)alloc((size_t)256 * FPIN * 2); // 1 MB
  __hip_bfloat16* descbf = (__hip_bfloat16*)alloc((size_t)G * 224 * 2);
  __hip_bfloat16* dwt    = (__hip_bfloat16*)alloc((size_t)64 * 224 * 2);
  __hip_bfloat16* k1wt   = (__hip_bfloat16*)alloc((size_t)192 * 384 * 2);
  __hip_bfloat16* zbuf   = (__hip_bfloat16*)alloc((size_t)G * 384 * 2);
  float* z1      = (float*)alloc((size_t)G * 192 * 4);
  float* P_fp    = (float*)alloc((size_t)4 * G * 256 * 4);             // 4 MB
  int*   deg     = (int*)alloc((size_t)N * 4);
  int*   csr_ptr = (int*)alloc((size_t)(N + 1) * 4);
  int*   cursor  = (int*)alloc((size_t)N * 4);
  int*   csr_src = (int*)alloc((size_t)E * 4);
  float* csr_ea  = (float*)alloc((size_t)E * 8 * 4);                  // 8 MB
  float* ea_mean = (float*)alloc((size_t)N * 8 * 4);                  // 1 MB
  int*   bsum    = (int*)alloc((size_t)64 * 4);
  (void)ws_size;

  const int* srcp = edge_index;
  const int* dstp = edge_index + E;
  const int nb = (N + 1023) / 1024;

  hipMemsetAsync(deg, 0, (size_t)N * 4, stream);

  // prep: vectorized conversions + transposes + k1wt + fwt + degree count
  {
    long total = (long)N * 8 + (long)G * 512 + 512 * 32 + 512 * 256 +
                 (long)G * 224 + 64 * 224 + 192 * 384 + 256 * 2048 + E;
    prep_kernel<<<(int)((total + 255) / 256), 256, 0, stream>>>(
        x, fp, c1_Wl, c1_Wr, c2_Wl, c2_Wr, desc, dW, k1W, fW, dstp, deg,
        xbf, fpbf, wt1, wt2, descbf, dwt, k1wt, fwt, N, G, E, DIN);
  }
  scan1_kernel<<<nb, 1024, 0, stream>>>(deg, csr_ptr, bsum, N);
  scan2_kernel<<<(N + 1 + 255) / 256, 256, 0, stream>>>(bsum, csr_ptr, cursor, N, nb);

  // MEGA1: CSR fill ∪ layer-1 GEMM ∪ fp split-K GEMM ∪ desc GEMM
  {
    int nblk = E / 256 + (N / 128) * 4 + (G / 64) * 16 + G / 64; // 1024+1024+256+16
    mega1_kernel<<<nblk, 256, 0, stream>>>(
        srcp, dstp, edge_attr, cursor, csr_src, csr_ea,
        xbf, wt1, c1_bl, c1_br, xlb, xrb,
        fpbf, fwt, P_fp, descbf, dwt, db, d_gn, d_bt, zbuf, N, G, E);
  }

  // MEGA2: ea_mean ∪ fp epilogue (deps: mega1)
  mega2_kernel<<<N * 8 / 256 + G, 256, 0, stream>>>(
      csr_ea, csr_ptr, ea_mean, P_fp, fb, f_gn, f_bt, zbuf, N, G);

  // layer 1 aggregation
  gat_kernel<<<N / 2, 128, 0, stream>>>(xlb, xrb, csr_ea, csr_src, csr_ptr, ea_mean,
                                        c1_We, c1_att, c1_bias, hb1, N);
  // layer 2
  gemm_mfma_kernel<<<dim3(N / 128, 4), 256, 0, stream>>>(hb1, wt2, c2_bl, c2_br, xlb, xrb, N, HC);
  gat_kernel<<<N / 2, 128, 0, stream>>>(xlb, xrb, csr_ea, csr_src, csr_ptr, ea_mean,
                                        c2_We, c2_att, c2_bias, hb2, N);

  // fused pool + g branch -> zbuf[:,0:64]
  poolg_kernel<<<G, 256, 0, stream>>>(hb2, gW, gb, g_gn, g_bt, zbuf, N / G);

  // k1 (bf16 MFMA) -> z1 fp32
  gemm_rb_kernel<<<dim3(G / 64, 3), 256, 0, stream>>>(zbuf, k1wt, k1b, k1_gn, k1_bt,
                                                      z1, G, 384, 192, 0, 0);
  // k2+k3 head
  head23_kernel<<<G / 8, 256, 0, stream>>>(z1, k2W, k2b, k2_gn, k2_bt, k3W, k3b,
                                           (float*)d_out);
}